// Round 3
// baseline (110.650 us; speedup 1.0000x reference)
//
#include <hip/hip_runtime.h>

// Problem constants (reference: S, B, D, MAX_LEN, P = 4096, 64, 256, 4096, 8)
#define S_LEN 4096
#define BATCH 64
#define DIM 256
#define NPEAK 8
#define TOTAL4 (S_LEN * BATCH * DIM / 4)     // 16,777,216 float4 elements
#define NTHREADS (2048 * 256)                // 2^19
#define ITERS (TOTAL4 / NTHREADS)            // 32 exactly
#define UNROLL 4

static_assert(TOTAL4 % NTHREADS == 0, "exact grid-stride trip count required");
static_assert(ITERS % UNROLL == 0, "unroll must divide trip count");

typedef float f32x4 __attribute__((ext_vector_type(4)));

// Fused: out[s,b,d] = x[s,b,d] + pe[s,d] + count(s,b) * table[s,d]
// count(s,b) = #{ j : peaks[b,j] == s }; invalid peaks (outside [0,S)) never
// match, so they contribute zero — matches reference semantics incl. dups.
//
// Layout invariants (grid*block = 2^19, stride = 2^19):
//   lane = d4  -> (s,b) uniform per wave, cnt-branch non-divergent
//   b, d4 invariant across iterations; s = (tid>>12) + it*128
//
// MLP: batch UNROLL=4 iterations — 4 independent x-loads + 4 pe-loads issued
// before the first store, 8 VMEM ops in flight per wave (vs ~2 rolled).
__global__ __launch_bounds__(256) void fused_pe_peak_kernel(
    const f32x4* __restrict__ x,
    const int*   __restrict__ peaks,
    const f32x4* __restrict__ pe,
    const f32x4* __restrict__ table,
    f32x4* __restrict__ out)
{
    const int tid = blockIdx.x * blockDim.x + threadIdx.x;
    const int b   = (tid >> 6) & (BATCH - 1);
    const int d4  = tid & (DIM / 4 - 1);
    const int s0  = tid >> 12;               // s at it=0; s(it) = s0 + it*128

    int pk[NPEAK];
    #pragma unroll
    for (int j = 0; j < NPEAK; ++j) pk[j] = peaks[b * NPEAK + j];

    #pragma unroll 1
    for (int it = 0; it < ITERS; it += UNROLL) {
        f32x4 xv[UNROLL], pv[UNROLL];

        #pragma unroll
        for (int u = 0; u < UNROLL; ++u) {
            const int i = tid + (it + u) * NTHREADS;
            xv[u] = __builtin_nontemporal_load(&x[i]);       // streamed
        }
        #pragma unroll
        for (int u = 0; u < UNROLL; ++u) {
            const int s = s0 + (it + u) * 128;
            pv[u] = pe[(s << 6) + d4];                       // L2-resident
        }
        #pragma unroll
        for (int u = 0; u < UNROLL; ++u) {
            const int s = s0 + (it + u) * 128;
            f32x4 o = xv[u] + pv[u];
            int cnt = 0;
            #pragma unroll
            for (int j = 0; j < NPEAK; ++j) cnt += (pk[j] == s) ? 1 : 0;
            if (cnt)                                          // wave-uniform, rare
                o += (float)cnt * table[(s << 6) + d4];
            __builtin_nontemporal_store(o, &out[tid + (it + u) * NTHREADS]);
        }
    }
}

extern "C" void kernel_launch(void* const* d_in, const int* in_sizes, int n_in,
                              void* d_out, int out_size, void* d_ws, size_t ws_size,
                              hipStream_t stream) {
    const float* x     = (const float*)d_in[0];   // [S, B, D] f32
    const int* peaks   = (const int*)d_in[1];     // [B, P] i32
    const float* pe    = (const float*)d_in[2];   // [MAX_LEN, 1, D] f32
    const float* table = (const float*)d_in[3];   // [MAX_LEN, D] f32

    // grid*block = 2^19 exactly: required for the b/d4/s0 hoisting invariants.
    fused_pe_peak_kernel<<<2048, 256, 0, stream>>>(
        (const f32x4*)x, peaks, (const f32x4*)pe, (const f32x4*)table,
        (f32x4*)d_out);
}

// Round 4
// 104.571 us; speedup vs baseline: 1.0581x; 1.0581x over previous
//
#include <hip/hip_runtime.h>

// Problem constants (reference: S, B, D, MAX_LEN, P = 4096, 64, 256, 4096, 8)
#define S_LEN 4096
#define BATCH 64
#define DIM 256
#define NPEAK 8
#define TOTAL4 (S_LEN * BATCH * DIM / 4)     // 16,777,216 float4 elements
#define NTHREADS (2048 * 256)                // 2^19
#define ITERS (TOTAL4 / NTHREADS)            // 32 exactly

static_assert(TOTAL4 % NTHREADS == 0, "exact grid-stride trip count required");

typedef float f32x4 __attribute__((ext_vector_type(4)));

// Fused: out[s,b,d] = x[s,b,d] + pe[s,d] + count(s,b) * table[s,d]
// count(s,b) = #{ j : peaks[b,j] == s }; invalid peaks (outside [0,S)) never
// match any s in [0,S), so they contribute zero — matches reference incl dups.
//
// Layout invariants (grid*block = stride = 2^19):
//   lane = d4 -> (s,b) uniform per wave, cnt branch non-divergent
//   b, d4 invariant across iterations; s = s0 + it*128
//
// Round-2 lesson: explicit unroll-4 REGRESSED (104 -> 110.6 us) — the
// compiler's rolled schedule + 8-waves/SIMD TLP already hides latency.
// Keep the loop rolled (#pragma unroll 1).
// This round's single change: plain (cached) stores instead of nontemporal —
// let the write stream batch through L2 like the 7 TB/s fill kernels do.
// Loads stay nontemporal (zero reuse; keeps pe/table resident in L2).
__global__ __launch_bounds__(256) void fused_pe_peak_kernel(
    const f32x4* __restrict__ x,
    const int*   __restrict__ peaks,
    const f32x4* __restrict__ pe,
    const f32x4* __restrict__ table,
    f32x4* __restrict__ out)
{
    const int tid = blockIdx.x * blockDim.x + threadIdx.x;
    const int b   = (tid >> 6) & (BATCH - 1);
    const int d4  = tid & (DIM / 4 - 1);
    const int s0  = tid >> 12;               // s(it) = s0 + it*128

    int pk[NPEAK];
    #pragma unroll
    for (int j = 0; j < NPEAK; ++j) pk[j] = peaks[b * NPEAK + j];

    #pragma unroll 1
    for (int it = 0; it < ITERS; ++it) {
        const int i = tid + it * NTHREADS;
        const int s = s0 + it * 128;
        f32x4 xv = __builtin_nontemporal_load(&x[i]);   // streamed, no reuse
        f32x4 pv = pe[(s << 6) + d4];                   // L1/L2-resident (1KB/row)
        f32x4 o = xv + pv;

        int cnt = 0;
        #pragma unroll
        for (int j = 0; j < NPEAK; ++j) cnt += (pk[j] == s) ? 1 : 0;
        if (cnt)                                         // wave-uniform, rare
            o += (float)cnt * table[(s << 6) + d4];

        out[i] = o;                                      // plain store via L2
    }
}

extern "C" void kernel_launch(void* const* d_in, const int* in_sizes, int n_in,
                              void* d_out, int out_size, void* d_ws, size_t ws_size,
                              hipStream_t stream) {
    const float* x     = (const float*)d_in[0];   // [S, B, D] f32
    const int* peaks   = (const int*)d_in[1];     // [B, P] i32
    const float* pe    = (const float*)d_in[2];   // [MAX_LEN, 1, D] f32
    const float* table = (const float*)d_in[3];   // [MAX_LEN, D] f32

    // grid*block = 2^19 exactly: required for the b/d4/s0 hoisting invariants.
    fused_pe_peak_kernel<<<2048, 256, 0, stream>>>(
        (const f32x4*)x, peaks, (const f32x4*)pe, (const f32x4*)table,
        (f32x4*)d_out);
}